// Round 9
// baseline (1373.853 us; speedup 1.0000x reference)
//
#include <hip/hip_runtime.h>
#include <hip/hip_bf16.h>

#define T 256
#define H 400
#define G4 1600   // 4*H
#define WD 300
#define TD 100
#define MLP_H 400
#define NBLK_D 25       // blocks per direction (50 total)
#define HB 16           // h-rows per block
#define GR 64           // gate-rows per block (4*HB)
#define WSTR 202        // LDS weight row stride in u32 (bank-conflict pad)
#define NPAIR 200       // 400 h values -> 200 tagged 64-bit words

typedef _Float16 f16;
typedef _Float16 half2t __attribute__((ext_vector_type(2)));
typedef unsigned long long u64;
typedef unsigned int u32;

// ---------- math helpers ----------
__device__ __forceinline__ float fexp(float x) {
    return __builtin_amdgcn_exp2f(x * 1.4426950408889634f);
}
__device__ __forceinline__ float sigf(float x) {
    return __builtin_amdgcn_rcpf(1.0f + fexp(-x));
}
__device__ __forceinline__ float tanhf_fast(float x) {
    return 1.0f - 2.0f * __builtin_amdgcn_rcpf(1.0f + fexp(2.0f * x));
}
__device__ __forceinline__ unsigned short f16bits(f16 x) {
    union { f16 h; unsigned short u; } v; v.h = x; return v.u;
}
__device__ __forceinline__ u32 packh2(float a, float b) {
    half2t hv; hv.x = (_Float16)a; hv.y = (_Float16)b;
    return __builtin_bit_cast(u32, hv);
}

#if __has_builtin(__builtin_amdgcn_fdot2)
__device__ __forceinline__ float dot2u(u32 a, u32 b, float c) {
    return __builtin_amdgcn_fdot2(__builtin_bit_cast(half2t, a),
                                  __builtin_bit_cast(half2t, b), c, false);
}
#else
__device__ __forceinline__ float dot2u(u32 a, u32 b, float c) {
    half2t x = __builtin_bit_cast(half2t, a), y = __builtin_bit_cast(half2t, b);
    return fmaf((float)x.y, (float)y.y, fmaf((float)x.x, (float)y.x, c));
}
#endif

// system-scope (sc0 sc1) plain ops: bypass L1/L2, serviced at the IC --
// coherent across XCDs without RMWs or fences.
__device__ __forceinline__ u64 sysload(const u64* p) {
    return __hip_atomic_load(p, __ATOMIC_RELAXED, __HIP_MEMORY_SCOPE_SYSTEM);
}
__device__ __forceinline__ void sysstore(u64* p, u64 v) {
    __hip_atomic_store(p, v, __ATOMIC_RELAXED, __HIP_MEMORY_SCOPE_SYSTEM);
}

// ---------- embedding gather ----------
__global__ void gather_k(const int* __restrict__ words, const int* __restrict__ tags,
                         const float* __restrict__ wemb, const float* __restrict__ temb,
                         float* __restrict__ x0) {
    int t = blockIdx.x;
    int w = words[t], g = tags[t];
    for (int c = threadIdx.x; c < H; c += 128) {
        float v = (c < WD) ? wemb[w * WD + c] : temb[g * TD + (c - WD)];
        x0[t * H + c] = v;
    }
}

// ---------- z-batched GEMM: two independent problems (e.g. fwd/bwd dir) in
// one launch via blockIdx.z -- runs them CONCURRENTLY instead of as two
// sequential stream launches at 39% CU utilization each.
__global__ __launch_bounds__(256) void gemm_tnz(
    const float* __restrict__ X, int ldx,
    const float* __restrict__ Wt, long wz, int ldw, int wofs0, int wstep,
    const float* __restrict__ bias1, int b1zs, int b1mask,
    const float* __restrict__ bias2, int b2zs, int b2mask,
    float* __restrict__ out, int ldo, long ozs, int Rt, int K) {
    __shared__ float Xs[64][17];
    __shared__ float Ws[64][17];
    const int tid = threadIdx.x;
    const int z = blockIdx.z;
    const float* Wtz = Wt + (size_t)z * wz;
    const int wofs = wofs0 + z * wstep;
    const float* b1 = (bias1 && ((b1mask >> z) & 1)) ? bias1 + (size_t)z * b1zs : nullptr;
    const float* b2 = (bias2 && ((b2mask >> z) & 1)) ? bias2 + (size_t)z * b2zs : nullptr;
    float* outz = out + (size_t)z * ozs;
    const int t0 = blockIdx.x * 64, r0 = blockIdx.y * 64;
    const int lr = tid >> 2, kq = (tid & 3) * 4;
    const int ti = tid >> 4, rj = tid & 15;
    float acc[4][4] = {};
    for (int k0 = 0; k0 < K; k0 += 16) {
        float4 xv = *(const float4*)(X + (size_t)(t0 + lr) * ldx + k0 + kq);
        Xs[lr][kq + 0] = xv.x; Xs[lr][kq + 1] = xv.y;
        Xs[lr][kq + 2] = xv.z; Xs[lr][kq + 3] = xv.w;
        int r = r0 + lr;
        float4 wv = make_float4(0.f, 0.f, 0.f, 0.f);
        if (r < Rt) wv = *(const float4*)(Wtz + (size_t)r * ldw + wofs + k0 + kq);
        Ws[lr][kq + 0] = wv.x; Ws[lr][kq + 1] = wv.y;
        Ws[lr][kq + 2] = wv.z; Ws[lr][kq + 3] = wv.w;
        __syncthreads();
#pragma unroll
        for (int k = 0; k < 16; k++) {
            float xr[4], wr[4];
#pragma unroll
            for (int m = 0; m < 4; m++) xr[m] = Xs[ti * 4 + m][k];
#pragma unroll
            for (int n = 0; n < 4; n++) wr[n] = Ws[rj * 4 + n][k];
#pragma unroll
            for (int m = 0; m < 4; m++)
#pragma unroll
                for (int n = 0; n < 4; n++)
                    acc[m][n] = fmaf(xr[m], wr[n], acc[m][n]);
        }
        __syncthreads();
    }
    int rq = r0 + rj * 4;
    if (rq < Rt) {
        float b[4];
#pragma unroll
        for (int n = 0; n < 4; n++) {
            int r = rq + n;
            b[n] = (b1 ? b1[r] : 0.f) + (b2 ? b2[r] : 0.f);
        }
#pragma unroll
        for (int m = 0; m < 4; m++) {
            int t = t0 + ti * 4 + m;
            float4 o;
            o.x = acc[m][0] + b[0]; o.y = acc[m][1] + b[1];
            o.z = acc[m][2] + b[2]; o.w = acc[m][3] + b[3];
            *(float4*)(outz + (size_t)t * ldo + rq) = o;
        }
    }
}

// ---------- init: tagged words, contiguous [dir][parity][NPAIR] ----------
__global__ void lstm_init5(const float* __restrict__ h0, u64* sA, u64* sB) {
    int tid = threadIdx.x;
    const int TOT = 2 * 2 * NPAIR;
    for (int i = tid; i < TOT; i += 256) { sA[i] = 0xFFFFULL; sB[i] = 0xFFFFULL; }
    __syncthreads();
    for (int p = tid; p < 2 * NPAIR; p += 256) {
        int d = p / NPAIR, pr = p - d * NPAIR;
        size_t off = (size_t)(d * 2 + 0) * NPAIR + pr;   // parity 0, tag 0
        f16 a0 = (f16)h0[d * H + 2 * pr], b0 = (f16)h0[d * H + 2 * pr + 1];
        sA[off] = 0ULL | ((u64)f16bits(a0) << 16) | ((u64)f16bits(b0) << 32);
        f16 a1 = (f16)h0[2 * H + d * H + 2 * pr], b1 = (f16)h0[2 * H + d * H + 2 * pr + 1];
        sB[off] = 0ULL | ((u64)f16bits(a1) << 16) | ((u64)f16bits(b1) << 32);
    }
}

// ---------- persistent LSTM layer v16: R8 structure + pipelined polling ----------
// Identical to the proven R0/R8 kernel except the poller spin: 4 loads to the
// same tagged word kept in flight (rotating retire-check-reissue). Steady-state
// sampling period drops from ~RT (load->vmcnt(0)->check) to ~RT/4 -- the
// detect-side quantization of the publish->detect latency shrinks by ~RT/2.
// Same-thread same-address loads complete in order; tags are monotonic; the
// R0 spin-escape RMW fallback is kept. Worst case (compiler forces vmcnt(0))
// degenerates to baseline sampling -- no regression axis.
__global__ __launch_bounds__(512, 1) void lstm_layer8(
    const float* __restrict__ G,     // [2][T][G4] gate inputs, biases folded
    const float* __restrict__ Whh,   // [2][G4][H]
    const float* __restrict__ c0l,   // [2][H] this layer
    float* __restrict__ xout,        // [T][2H]
    u64* __restrict__ slots) {       // [2][2][NPAIR]
    const int role = blockIdx.x;
    const int dir = role / NBLK_D, blk = role - dir * NBLK_D;
    const int tid = threadIdx.x;
    const float* Wd = Whh + (size_t)dir * G4 * H;
    const float* Gd = G + (size_t)dir * T * G4;
    u64* sd = slots + (size_t)dir * 2 * NPAIR;

    __shared__ u32 wlds[GR * WSTR];            // 64 rows x 202 u32 = 50.5 KiB
    __shared__ __align__(16) u32 hsh[NPAIR];   // h_s as 200 packed half2
    __shared__ float gsum[GR];                 // per-gate-row matvec sums
    __shared__ float gsh[2][GR];               // staged G, double-buffered

    // ---- one-time: pack weights fp32 -> half2 into LDS ----
    for (int idx = tid; idx < GR * 100; idx += 512) {
        int row = idx / 100, c4 = idx - row * 100;
        int g = row >> 4, r = row & 15;
        const float4* src = (const float4*)(Wd + (size_t)(g * H + blk * HB + r) * H);
        float4 f = src[c4];
        *(uint2*)&wlds[row * WSTR + c4 * 2] =
            make_uint2(packh2(f.x, f.y), packh2(f.z, f.w));
    }
    // pre-stage G(0); own h0 words into LDS
    if (tid >= 448) {
        int i = tid - 448, gg = i >> 4, rr = i & 15;
        int tt0 = dir ? (T - 1) : 0;
        gsh[0][i] = Gd[(size_t)tt0 * G4 + gg * H + blk * HB + rr];
    } else if (tid < 8) {
        u64 v = sysload(sd + blk * 8 + tid);       // parity 0, tag 0
        hsh[blk * 8 + tid] = (u32)(v >> 16);
    }
    float c = (tid < 64) ? c0l[dir * H + blk * HB + (tid & 15)] : 0.f;
    __syncthreads();

#pragma clang loop unroll(disable)
    for (int s = 0; s < T; ++s) {
        if (tid >= 256 && tid < 448) {
            // poller: one foreign word (parity s&1, tag s), 4-deep pipelined spin
            int f = tid - 256;
            int widx = f + (f >= blk * 8 ? 8 : 0);
            u64* src = sd + (size_t)(s & 1) * NPAIR + widx;
            const unsigned su = (unsigned)s;
            u64 v;
            u64 v0 = sysload(src);
            u64 v1 = sysload(src);
            u64 v2 = sysload(src);
            u64 v3 = sysload(src);
            int spins = 0;
            for (;;) {
                if ((unsigned)(v0 & 0xFFFFULL) == su) { v = v0; break; }
                v0 = sysload(src);
                if ((unsigned)(v1 & 0xFFFFULL) == su) { v = v1; break; }
                v1 = sysload(src);
                if ((unsigned)(v2 & 0xFFFFULL) == su) { v = v2; break; }
                v2 = sysload(src);
                if ((unsigned)(v3 & 0xFFFFULL) == su) { v = v3; break; }
                if (++spins > 4096) {
                    v3 = __hip_atomic_fetch_add(src, 0ULL, __ATOMIC_RELAXED,
                                                __HIP_MEMORY_SCOPE_AGENT);
                } else {
                    v3 = sysload(src);
                }
            }
            hsh[widx] = (u32)(v >> 16);
        } else if (tid >= 448) {
            // stager: G(s+1) into the other parity half
            int sn = (s + 1 < T) ? (s + 1) : s;
            int tt = dir ? (T - 1 - sn) : sn;
            int i = tid - 448, gg = i >> 4, rr = i & 15;
            gsh[(s + 1) & 1][i] = Gd[(size_t)tt * G4 + gg * H + blk * HB + rr];
        }
        __syncthreads();   // (A) h_s complete in LDS

        if (tid < 256) {
            const int row = tid >> 2, sl = tid & 3;
            const u32* wp = &wlds[row * WSTR + sl * 50];
            const u32* hp = &hsh[sl * 50];
            float a0 = 0.f, a1 = 0.f, a2 = 0.f, a3 = 0.f;
#pragma unroll
            for (int i = 0; i < 12; ++i) {
                uint2 wv0 = *(const uint2*)&wp[4 * i];
                uint2 hv0 = *(const uint2*)&hp[4 * i];
                uint2 wv1 = *(const uint2*)&wp[4 * i + 2];
                uint2 hv1 = *(const uint2*)&hp[4 * i + 2];
                a0 = dot2u(wv0.x, hv0.x, a0);
                a1 = dot2u(wv0.y, hv0.y, a1);
                a2 = dot2u(wv1.x, hv1.x, a2);
                a3 = dot2u(wv1.y, hv1.y, a3);
            }
            {
                uint2 wv = *(const uint2*)&wp[48];
                uint2 hv = *(const uint2*)&hp[48];
                a0 = dot2u(wv.x, hv.x, a0);
                a1 = dot2u(wv.y, hv.y, a1);
            }
            float a = (a0 + a1) + (a2 + a3);
            a += __shfl_xor(a, 1);    // combine the 4 k-slices (adjacent lanes)
            a += __shfl_xor(a, 2);
            if (sl == 0) gsum[row] = a;
        }
        __syncthreads();   // (B) sums ready

        if (tid < 64) {    // wave 0: gate math + publish, intra-wave only
            const int r = tid & 15;
            const float* gc = gsh[s & 1];
            float iv = gsum[r]      + gc[r];
            float fv = gsum[16 + r] + gc[16 + r];
            float gv = gsum[32 + r] + gc[32 + r];
            float ov = gsum[48 + r] + gc[48 + r];
            float cn = sigf(fv) * c + sigf(iv) * tanhf_fast(gv);
            c = cn;
            float hn = sigf(ov) * tanhf_fast(cn);
            u32 hb = (u32)f16bits((f16)hn);
            u32 lo = __shfl(hb, (2 * tid) & 63);
            u32 hi = __shfl(hb, (2 * tid + 1) & 63);
            if (tid < 8) {
                u32 pk = (lo & 0xFFFFu) | (hi << 16);
                hsh[blk * 8 + tid] = pk;   // own slice of h_{s+1}, LDS fast-path
                sysstore(sd + (size_t)((s + 1) & 1) * NPAIR + blk * 8 + tid,
                         (u64)(unsigned)(s + 1) | ((u64)pk << 16));
            }
            const int tt = dir ? (T - 1 - s) : s;
            if (tid < 16)
                xout[(size_t)tt * (2 * H) + dir * H + blk * HB + tid] = hn;
        }
    }
}

// ---------- fused pairwise scorer ----------
__global__ __launch_bounds__(256) void scores_k(
    const float* __restrict__ pi, const float* __restrict__ pj,
    const float* __restrict__ w2, const float* __restrict__ b2p,
    float* __restrict__ out) {
    __shared__ float Ps[16][401];
    __shared__ float Qs[16][401];
    __shared__ float w2s[400];
    const int tid = threadIdx.x;
    const int i0 = blockIdx.y * 16, j0 = blockIdx.x * 16;
    for (int r = 0; r < 16; r++) {
        for (int k = tid; k < MLP_H; k += 256) {
            Ps[r][k] = pi[(size_t)(i0 + r) * MLP_H + k];
            Qs[r][k] = pj[(size_t)(j0 + r) * MLP_H + k];
        }
    }
    for (int k = tid; k < MLP_H; k += 256) w2s[k] = w2[k];
    __syncthreads();
    const int ti = tid >> 4, tj = tid & 15;
    float acc = 0.f;
#pragma unroll 4
    for (int k = 0; k < MLP_H; k++) {
        float x = Ps[ti][k] + Qs[tj][k];
        acc = fmaf(w2s[k], tanhf_fast(x), acc);
    }
    const int i = i0 + ti, j = j0 + tj;
    out[(size_t)i * T + j] = (i == j) ? 0.f : (acc + b2p[0]);
}

extern "C" void kernel_launch(void* const* d_in, const int* in_sizes, int n_in,
                              void* d_out, int out_size, void* d_ws, size_t ws_size,
                              hipStream_t stream) {
    const int*   words = (const int*)d_in[0];
    const int*   tags  = (const int*)d_in[1];
    const float* wemb  = (const float*)d_in[2];
    const float* temb  = (const float*)d_in[3];
    const float* Wih0  = (const float*)d_in[4];
    const float* Whh0  = (const float*)d_in[5];
    const float* bih0  = (const float*)d_in[6];
    const float* bhh0  = (const float*)d_in[7];
    const float* Wih1  = (const float*)d_in[8];
    const float* Whh1  = (const float*)d_in[9];
    const float* bih1  = (const float*)d_in[10];
    const float* bhh1  = (const float*)d_in[11];
    const float* W1    = (const float*)d_in[12];
    const float* b1    = (const float*)d_in[13];
    const float* W2    = (const float*)d_in[14];
    const float* b2    = (const float*)d_in[15];
    const float* h0    = (const float*)d_in[16];
    const float* c0    = (const float*)d_in[17];
    float* out = (float*)d_out;

    float* W = (float*)d_ws;
    float* x0   = W;                 // 256*400 (dead after layer-0 GEMMs)
    float* x1   = W + 102400;        // 256*800
    float* hvec = W + 307200;        // 256*800
    float* Gb   = W + 512000;        // 2*256*1600 (reused for both layers)
    float* pi   = W + 1331200;       // 256*400
    float* pj   = W + 1433600;       // 256*400 (pj = pi + 102400)
    // word arrays overlap x0's region (x0 dead before lstm_init5 runs)
    u64* slotsA = (u64*)W;                               // 800 u64
    u64* slotsB = (u64*)(W + 2048);                      // 800 u64

    // 1. embedding gather
    gather_k<<<T, 128, 0, stream>>>(words, tags, wemb, temb, x0);

    // 2. layer-0 gate inputs, BOTH dirs in one launch (z = dir)
    gemm_tnz<<<dim3(4, 25, 2), 256, 0, stream>>>(
        x0, H, Wih0, (long)G4 * H, H, 0, 0,
        bih0, G4, 3, bhh0, G4, 3,
        Gb, G4, (long)T * G4, G4, H);

    // 3. init tagged words (x0 now dead), then LSTM layer 0
    lstm_init5<<<1, 256, 0, stream>>>(h0, slotsA, slotsB);
    lstm_layer8<<<2 * NBLK_D, 512, 0, stream>>>(Gb, Whh0, c0, x1, slotsA);

    // 4. layer-1 gate inputs (K=800), BOTH dirs in one launch
    gemm_tnz<<<dim3(4, 25, 2), 256, 0, stream>>>(
        x1, 2 * H, Wih1, (long)G4 * 2 * H, 2 * H, 0, 0,
        bih1, G4, 3, bhh1, G4, 3,
        Gb, G4, (long)T * G4, G4, 2 * H);

    // 5. LSTM layer 1
    lstm_layer8<<<2 * NBLK_D, 512, 0, stream>>>(Gb, Whh1, c0 + 2 * H, hvec, slotsB);

    // 6. pi and pj in ONE launch (z: 0 -> pi with b1, 1 -> pj, W1 col-offset 2H)
    gemm_tnz<<<dim3(4, 7, 2), 256, 0, stream>>>(
        hvec, 2 * H, W1, 0L, G4, 0, 2 * H,
        b1, 0, 1, nullptr, 0, 0,
        pi, MLP_H, 102400L, MLP_H, 2 * H);

    // 7. fused pairwise scores
    scores_k<<<dim3(16, 16), 256, 0, stream>>>(pi, pj, W2, b2, out);
}

// Round 10
// 1317.029 us; speedup vs baseline: 1.0431x; 1.0431x over previous
//
#include <hip/hip_runtime.h>
#include <hip/hip_bf16.h>

#define T 256
#define H 400
#define G4 1600   // 4*H
#define WD 300
#define TD 100
#define MLP_H 400
#define NBLK_D 25       // blocks per direction (50 total)
#define HB 16           // h-rows per block
#define GR 64           // gate-rows per block (4*HB)
#define WSTR 202        // LDS weight row stride in u32 (bank-conflict pad)
#define NPAIR 200       // 400 h values -> 200 tagged 64-bit words

typedef _Float16 f16;
typedef _Float16 half2t __attribute__((ext_vector_type(2)));
typedef unsigned long long u64;
typedef unsigned int u32;

// ---------- math helpers ----------
__device__ __forceinline__ float fexp(float x) {
    return __builtin_amdgcn_exp2f(x * 1.4426950408889634f);
}
__device__ __forceinline__ float sigf(float x) {
    return __builtin_amdgcn_rcpf(1.0f + fexp(-x));
}
__device__ __forceinline__ float tanhf_fast(float x) {
    return 1.0f - 2.0f * __builtin_amdgcn_rcpf(1.0f + fexp(2.0f * x));
}
__device__ __forceinline__ unsigned short f16bits(f16 x) {
    union { f16 h; unsigned short u; } v; v.h = x; return v.u;
}
__device__ __forceinline__ u32 packh2(float a, float b) {
    half2t hv; hv.x = (_Float16)a; hv.y = (_Float16)b;
    return __builtin_bit_cast(u32, hv);
}

#if __has_builtin(__builtin_amdgcn_fdot2)
__device__ __forceinline__ float dot2u(u32 a, u32 b, float c) {
    return __builtin_amdgcn_fdot2(__builtin_bit_cast(half2t, a),
                                  __builtin_bit_cast(half2t, b), c, false);
}
#else
__device__ __forceinline__ float dot2u(u32 a, u32 b, float c) {
    half2t x = __builtin_bit_cast(half2t, a), y = __builtin_bit_cast(half2t, b);
    return fmaf((float)x.y, (float)y.y, fmaf((float)x.x, (float)y.x, c));
}
#endif

// system-scope (sc0 sc1) plain ops: bypass L1/L2, serviced at the IC --
// coherent across XCDs without RMWs or fences.
__device__ __forceinline__ u64 sysload(const u64* p) {
    return __hip_atomic_load(p, __ATOMIC_RELAXED, __HIP_MEMORY_SCOPE_SYSTEM);
}
__device__ __forceinline__ void sysstore(u64* p, u64 v) {
    __hip_atomic_store(p, v, __ATOMIC_RELAXED, __HIP_MEMORY_SCOPE_SYSTEM);
}

// ---------- fused layer-0 gate GEMM: embedding gather folded into X-stage,
// tagged-word init folded into the spare y=25 grid row. Saves two launches
// (~30-40us each in this harness) and never materializes x0.
// grid (4, 26, 2): y<25 compute G[z][t][r] = emb(t) . Wih0[z][r] + biases;
// y==25, x==0, z==0 runs the slot init; other y==25 blocks exit.
__global__ __launch_bounds__(256) void gemm_l0(
    const int* __restrict__ words, const int* __restrict__ tags,
    const float* __restrict__ wemb, const float* __restrict__ temb,
    const float* __restrict__ Wt,    // Wih0 [2][G4][H]
    const float* __restrict__ bias1, // bih0 [2][G4]
    const float* __restrict__ bias2, // bhh0 [2][G4]
    float* __restrict__ out,         // Gb [2][T][G4]
    const float* __restrict__ h0, u64* sA, u64* sB) {
    const int tid = threadIdx.x;
    const int z = blockIdx.z;
    const int t0 = blockIdx.x * 64, r0 = blockIdx.y * 64;

    if (r0 >= G4) {
        // ---- init block: tagged words for both layers ----
        if (blockIdx.x != 0 || z != 0) return;
        const int TOT = 2 * 2 * NPAIR;
        for (int i = tid; i < TOT; i += 256) { sA[i] = 0xFFFFULL; sB[i] = 0xFFFFULL; }
        __syncthreads();
        for (int p = tid; p < 2 * NPAIR; p += 256) {
            int d = p / NPAIR, pr = p - d * NPAIR;
            size_t off = (size_t)(d * 2 + 0) * NPAIR + pr;   // parity 0, tag 0
            f16 a0 = (f16)h0[d * H + 2 * pr], b0 = (f16)h0[d * H + 2 * pr + 1];
            sA[off] = 0ULL | ((u64)f16bits(a0) << 16) | ((u64)f16bits(b0) << 32);
            f16 a1 = (f16)h0[2 * H + d * H + 2 * pr], b1 = (f16)h0[2 * H + d * H + 2 * pr + 1];
            sB[off] = 0ULL | ((u64)f16bits(a1) << 16) | ((u64)f16bits(b1) << 32);
        }
        return;
    }

    __shared__ float Xs[64][17];
    __shared__ float Ws[64][17];
    __shared__ int wsh[64], tsh[64];
    const float* Wtz = Wt + (size_t)z * G4 * H;
    const float* b1 = bias1 + (size_t)z * G4;
    const float* b2 = bias2 + (size_t)z * G4;
    float* outz = out + (size_t)z * T * G4;
    const int lr = tid >> 2, kq = (tid & 3) * 4;
    const int ti = tid >> 4, rj = tid & 15;
    if (tid < 64) { wsh[tid] = words[t0 + tid]; tsh[tid] = tags[t0 + tid]; }
    __syncthreads();
    float acc[4][4] = {};
    for (int k0 = 0; k0 < H; k0 += 16) {
        int k = k0 + kq;
        // embedding gather inline (float4 never straddles WD: 300 % 4 == 0)
        float4 xv = (k < WD)
            ? *(const float4*)(wemb + (size_t)wsh[lr] * WD + k)
            : *(const float4*)(temb + (size_t)tsh[lr] * TD + (k - WD));
        Xs[lr][kq + 0] = xv.x; Xs[lr][kq + 1] = xv.y;
        Xs[lr][kq + 2] = xv.z; Xs[lr][kq + 3] = xv.w;
        int r = r0 + lr;
        float4 wv = *(const float4*)(Wtz + (size_t)r * H + k);
        Ws[lr][kq + 0] = wv.x; Ws[lr][kq + 1] = wv.y;
        Ws[lr][kq + 2] = wv.z; Ws[lr][kq + 3] = wv.w;
        __syncthreads();
#pragma unroll
        for (int kk = 0; kk < 16; kk++) {
            float xr[4], wr[4];
#pragma unroll
            for (int m = 0; m < 4; m++) xr[m] = Xs[ti * 4 + m][kk];
#pragma unroll
            for (int n = 0; n < 4; n++) wr[n] = Ws[rj * 4 + n][kk];
#pragma unroll
            for (int m = 0; m < 4; m++)
#pragma unroll
                for (int n = 0; n < 4; n++)
                    acc[m][n] = fmaf(xr[m], wr[n], acc[m][n]);
        }
        __syncthreads();
    }
    int rq = r0 + rj * 4;
    {
        float b[4];
#pragma unroll
        for (int n = 0; n < 4; n++) { int r = rq + n; b[n] = b1[r] + b2[r]; }
#pragma unroll
        for (int m = 0; m < 4; m++) {
            int t = t0 + ti * 4 + m;
            float4 o;
            o.x = acc[m][0] + b[0]; o.y = acc[m][1] + b[1];
            o.z = acc[m][2] + b[2]; o.w = acc[m][3] + b[3];
            *(float4*)(outz + (size_t)t * G4 + rq) = o;
        }
    }
}

// ---------- z-batched GEMM: two independent problems (e.g. fwd/bwd dir) in
// one launch via blockIdx.z -- runs them CONCURRENTLY instead of as two
// sequential stream launches at 39% CU utilization each.
__global__ __launch_bounds__(256) void gemm_tnz(
    const float* __restrict__ X, int ldx,
    const float* __restrict__ Wt, long wz, int ldw, int wofs0, int wstep,
    const float* __restrict__ bias1, int b1zs, int b1mask,
    const float* __restrict__ bias2, int b2zs, int b2mask,
    float* __restrict__ out, int ldo, long ozs, int Rt, int K) {
    __shared__ float Xs[64][17];
    __shared__ float Ws[64][17];
    const int tid = threadIdx.x;
    const int z = blockIdx.z;
    const float* Wtz = Wt + (size_t)z * wz;
    const int wofs = wofs0 + z * wstep;
    const float* b1 = (bias1 && ((b1mask >> z) & 1)) ? bias1 + (size_t)z * b1zs : nullptr;
    const float* b2 = (bias2 && ((b2mask >> z) & 1)) ? bias2 + (size_t)z * b2zs : nullptr;
    float* outz = out + (size_t)z * ozs;
    const int t0 = blockIdx.x * 64, r0 = blockIdx.y * 64;
    const int lr = tid >> 2, kq = (tid & 3) * 4;
    const int ti = tid >> 4, rj = tid & 15;
    float acc[4][4] = {};
    for (int k0 = 0; k0 < K; k0 += 16) {
        float4 xv = *(const float4*)(X + (size_t)(t0 + lr) * ldx + k0 + kq);
        Xs[lr][kq + 0] = xv.x; Xs[lr][kq + 1] = xv.y;
        Xs[lr][kq + 2] = xv.z; Xs[lr][kq + 3] = xv.w;
        int r = r0 + lr;
        float4 wv = make_float4(0.f, 0.f, 0.f, 0.f);
        if (r < Rt) wv = *(const float4*)(Wtz + (size_t)r * ldw + wofs + k0 + kq);
        Ws[lr][kq + 0] = wv.x; Ws[lr][kq + 1] = wv.y;
        Ws[lr][kq + 2] = wv.z; Ws[lr][kq + 3] = wv.w;
        __syncthreads();
#pragma unroll
        for (int k = 0; k < 16; k++) {
            float xr[4], wr[4];
#pragma unroll
            for (int m = 0; m < 4; m++) xr[m] = Xs[ti * 4 + m][k];
#pragma unroll
            for (int n = 0; n < 4; n++) wr[n] = Ws[rj * 4 + n][k];
#pragma unroll
            for (int m = 0; m < 4; m++)
#pragma unroll
                for (int n = 0; n < 4; n++)
                    acc[m][n] = fmaf(xr[m], wr[n], acc[m][n]);
        }
        __syncthreads();
    }
    int rq = r0 + rj * 4;
    if (rq < Rt) {
        float b[4];
#pragma unroll
        for (int n = 0; n < 4; n++) {
            int r = rq + n;
            b[n] = (b1 ? b1[r] : 0.f) + (b2 ? b2[r] : 0.f);
        }
#pragma unroll
        for (int m = 0; m < 4; m++) {
            int t = t0 + ti * 4 + m;
            float4 o;
            o.x = acc[m][0] + b[0]; o.y = acc[m][1] + b[1];
            o.z = acc[m][2] + b[2]; o.w = acc[m][3] + b[3];
            *(float4*)(outz + (size_t)t * ldo + rq) = o;
        }
    }
}

// ---------- persistent LSTM layer v8 (R0/R8-proven, best known: 508us/layer) ----------
// grid = 50 blocks (dir = b/25, blk = b%25), 512 threads. Block owns h rows
// [blk*16,+16) = 64 gate-rows. Weights live in LDS (50.5 KiB, loaded once).
// tid<256: workers, 4 per gate-row; tid in [256,448): pollers for the 192
// foreign tagged words (IC-scope sc0/sc1 scheme); tid>=448: G stagers.
// Wave 0 does gate math + publish via intra-wave shuffles. 2 barriers/step.
// R9's 4-deep pipelined polling REGRESSED (+54us: extra IC traffic inflates
// the RT it samples) -- poller kept as the simple proven spin.
__global__ __launch_bounds__(512, 1) void lstm_layer8(
    const float* __restrict__ G,     // [2][T][G4] gate inputs, biases folded
    const float* __restrict__ Whh,   // [2][G4][H]
    const float* __restrict__ c0l,   // [2][H] this layer
    float* __restrict__ xout,        // [T][2H]
    u64* __restrict__ slots) {       // [2][2][NPAIR]
    const int role = blockIdx.x;
    const int dir = role / NBLK_D, blk = role - dir * NBLK_D;
    const int tid = threadIdx.x;
    const float* Wd = Whh + (size_t)dir * G4 * H;
    const float* Gd = G + (size_t)dir * T * G4;
    u64* sd = slots + (size_t)dir * 2 * NPAIR;

    __shared__ u32 wlds[GR * WSTR];            // 64 rows x 202 u32 = 50.5 KiB
    __shared__ __align__(16) u32 hsh[NPAIR];   // h_s as 200 packed half2
    __shared__ float gsum[GR];                 // per-gate-row matvec sums
    __shared__ float gsh[2][GR];               // staged G, double-buffered

    // ---- one-time: pack weights fp32 -> half2 into LDS ----
    for (int idx = tid; idx < GR * 100; idx += 512) {
        int row = idx / 100, c4 = idx - row * 100;
        int g = row >> 4, r = row & 15;
        const float4* src = (const float4*)(Wd + (size_t)(g * H + blk * HB + r) * H);
        float4 f = src[c4];
        *(uint2*)&wlds[row * WSTR + c4 * 2] =
            make_uint2(packh2(f.x, f.y), packh2(f.z, f.w));
    }
    // pre-stage G(0); own h0 words into LDS
    if (tid >= 448) {
        int i = tid - 448, gg = i >> 4, rr = i & 15;
        int tt0 = dir ? (T - 1) : 0;
        gsh[0][i] = Gd[(size_t)tt0 * G4 + gg * H + blk * HB + rr];
    } else if (tid < 8) {
        u64 v = sysload(sd + blk * 8 + tid);       // parity 0, tag 0
        hsh[blk * 8 + tid] = (u32)(v >> 16);
    }
    float c = (tid < 64) ? c0l[dir * H + blk * HB + (tid & 15)] : 0.f;
    __syncthreads();

#pragma clang loop unroll(disable)
    for (int s = 0; s < T; ++s) {
        if (tid >= 256 && tid < 448) {
            // poller: one foreign word (parity s&1, tag s)
            int f = tid - 256;
            int widx = f + (f >= blk * 8 ? 8 : 0);
            u64* src = sd + (size_t)(s & 1) * NPAIR + widx;
            u64 v = sysload(src);
            int spins = 0;
            while ((unsigned)(v & 0xFFFFULL) != (unsigned)s) {
                if (++spins > 16384) {
                    v = __hip_atomic_fetch_add(src, 0ULL, __ATOMIC_RELAXED,
                                               __HIP_MEMORY_SCOPE_AGENT);
                } else {
                    v = sysload(src);
                }
            }
            hsh[widx] = (u32)(v >> 16);
        } else if (tid >= 448) {
            // stager: G(s+1) into the other parity half
            int sn = (s + 1 < T) ? (s + 1) : s;
            int tt = dir ? (T - 1 - sn) : sn;
            int i = tid - 448, gg = i >> 4, rr = i & 15;
            gsh[(s + 1) & 1][i] = Gd[(size_t)tt * G4 + gg * H + blk * HB + rr];
        }
        __syncthreads();   // (A) h_s complete in LDS

        if (tid < 256) {
            const int row = tid >> 2, sl = tid & 3;
            const u32* wp = &wlds[row * WSTR + sl * 50];
            const u32* hp = &hsh[sl * 50];
            float a0 = 0.f, a1 = 0.f, a2 = 0.f, a3 = 0.f;
#pragma unroll
            for (int i = 0; i < 12; ++i) {
                uint2 wv0 = *(const uint2*)&wp[4 * i];
                uint2 hv0 = *(const uint2*)&hp[4 * i];
                uint2 wv1 = *(const uint2*)&wp[4 * i + 2];
                uint2 hv1 = *(const uint2*)&hp[4 * i + 2];
                a0 = dot2u(wv0.x, hv0.x, a0);
                a1 = dot2u(wv0.y, hv0.y, a1);
                a2 = dot2u(wv1.x, hv1.x, a2);
                a3 = dot2u(wv1.y, hv1.y, a3);
            }
            {
                uint2 wv = *(const uint2*)&wp[48];
                uint2 hv = *(const uint2*)&hp[48];
                a0 = dot2u(wv.x, hv.x, a0);
                a1 = dot2u(wv.y, hv.y, a1);
            }
            float a = (a0 + a1) + (a2 + a3);
            a += __shfl_xor(a, 1);    // combine the 4 k-slices (adjacent lanes)
            a += __shfl_xor(a, 2);
            if (sl == 0) gsum[row] = a;
        }
        __syncthreads();   // (B) sums ready

        if (tid < 64) {    // wave 0: gate math + publish, intra-wave only
            const int r = tid & 15;
            const float* gc = gsh[s & 1];
            float iv = gsum[r]      + gc[r];
            float fv = gsum[16 + r] + gc[16 + r];
            float gv = gsum[32 + r] + gc[32 + r];
            float ov = gsum[48 + r] + gc[48 + r];
            float cn = sigf(fv) * c + sigf(iv) * tanhf_fast(gv);
            c = cn;
            float hn = sigf(ov) * tanhf_fast(cn);
            u32 hb = (u32)f16bits((f16)hn);
            u32 lo = __shfl(hb, (2 * tid) & 63);
            u32 hi = __shfl(hb, (2 * tid + 1) & 63);
            if (tid < 8) {
                u32 pk = (lo & 0xFFFFu) | (hi << 16);
                hsh[blk * 8 + tid] = pk;   // own slice of h_{s+1}, LDS fast-path
                sysstore(sd + (size_t)((s + 1) & 1) * NPAIR + blk * 8 + tid,
                         (u64)(unsigned)(s + 1) | ((u64)pk << 16));
            }
            const int tt = dir ? (T - 1 - s) : s;
            if (tid < 16)
                xout[(size_t)tt * (2 * H) + dir * H + blk * HB + tid] = hn;
        }
    }
}

// ---------- fused pairwise scorer ----------
__global__ __launch_bounds__(256) void scores_k(
    const float* __restrict__ pi, const float* __restrict__ pj,
    const float* __restrict__ w2, const float* __restrict__ b2p,
    float* __restrict__ out) {
    __shared__ float Ps[16][401];
    __shared__ float Qs[16][401];
    __shared__ float w2s[400];
    const int tid = threadIdx.x;
    const int i0 = blockIdx.y * 16, j0 = blockIdx.x * 16;
    for (int r = 0; r < 16; r++) {
        for (int k = tid; k < MLP_H; k += 256) {
            Ps[r][k] = pi[(size_t)(i0 + r) * MLP_H + k];
            Qs[r][k] = pj[(size_t)(j0 + r) * MLP_H + k];
        }
    }
    for (int k = tid; k < MLP_H; k += 256) w2s[k] = w2[k];
    __syncthreads();
    const int ti = tid >> 4, tj = tid & 15;
    float acc = 0.f;
#pragma unroll 4
    for (int k = 0; k < MLP_H; k++) {
        float x = Ps[ti][k] + Qs[tj][k];
        acc = fmaf(w2s[k], tanhf_fast(x), acc);
    }
    const int i = i0 + ti, j = j0 + tj;
    out[(size_t)i * T + j] = (i == j) ? 0.f : (acc + b2p[0]);
}

extern "C" void kernel_launch(void* const* d_in, const int* in_sizes, int n_in,
                              void* d_out, int out_size, void* d_ws, size_t ws_size,
                              hipStream_t stream) {
    const int*   words = (const int*)d_in[0];
    const int*   tags  = (const int*)d_in[1];
    const float* wemb  = (const float*)d_in[2];
    const float* temb  = (const float*)d_in[3];
    const float* Wih0  = (const float*)d_in[4];
    const float* Whh0  = (const float*)d_in[5];
    const float* bih0  = (const float*)d_in[6];
    const float* bhh0  = (const float*)d_in[7];
    const float* Wih1  = (const float*)d_in[8];
    const float* Whh1  = (const float*)d_in[9];
    const float* bih1  = (const float*)d_in[10];
    const float* bhh1  = (const float*)d_in[11];
    const float* W1    = (const float*)d_in[12];
    const float* b1    = (const float*)d_in[13];
    const float* W2    = (const float*)d_in[14];
    const float* b2    = (const float*)d_in[15];
    const float* h0    = (const float*)d_in[16];
    const float* c0    = (const float*)d_in[17];
    float* out = (float*)d_out;

    float* W = (float*)d_ws;
    float* x1   = W + 102400;        // 256*800
    float* hvec = W + 307200;        // 256*800
    float* Gb   = W + 512000;        // 2*256*1600 (reused for both layers)
    float* pi   = W + 1331200;       // 256*400
    float* pj   = W + 1433600;       // 256*400 (pj = pi + 102400)
    u64* slotsA = (u64*)W;                               // 800 u64
    u64* slotsB = (u64*)(W + 2048);                      // 800 u64

    // 1. layer-0 gate inputs with fused embedding gather + slot init
    //    (grid y=26: y<25 GEMM, y==25 init; saves gather_k + lstm_init5 launches)
    gemm_l0<<<dim3(4, 26, 2), 256, 0, stream>>>(
        words, tags, wemb, temb, Wih0, bih0, bhh0, Gb, h0, slotsA, slotsB);

    // 2. LSTM layer 0
    lstm_layer8<<<2 * NBLK_D, 512, 0, stream>>>(Gb, Whh0, c0, x1, slotsA);

    // 3. layer-1 gate inputs (K=800), BOTH dirs in one launch
    gemm_tnz<<<dim3(4, 25, 2), 256, 0, stream>>>(
        x1, 2 * H, Wih1, (long)G4 * 2 * H, 2 * H, 0, 0,
        bih1, G4, 3, bhh1, G4, 3,
        Gb, G4, (long)T * G4, G4, 2 * H);

    // 4. LSTM layer 1
    lstm_layer8<<<2 * NBLK_D, 512, 0, stream>>>(Gb, Whh1, c0 + 2 * H, hvec, slotsB);

    // 5. pi and pj in ONE launch (z: 0 -> pi with b1, 1 -> pj, W1 col-offset 2H)
    gemm_tnz<<<dim3(4, 7, 2), 256, 0, stream>>>(
        hvec, 2 * H, W1, 0L, G4, 0, 2 * H,
        b1, 0, 1, nullptr, 0, 0,
        pi, MLP_H, 102400L, MLP_H, 2 * H);

    // 6. fused pairwise scores
    scores_k<<<dim3(16, 16), 256, 0, stream>>>(pi, pj, W2, b2, out);
}

// Round 11
// 1260.724 us; speedup vs baseline: 1.0897x; 1.0447x over previous
//
#include <hip/hip_runtime.h>
#include <hip/hip_bf16.h>

#define T 256
#define H 400
#define G4 1600   // 4*H
#define WD 300
#define TD 100
#define MLP_H 400
#define NBLK_D 25       // blocks per direction (50 total)
#define HB 16           // h-rows per block
#define GR 64           // gate-rows per block (4*HB)
#define WSTR 202        // LDS weight row stride in u32 (bank-conflict pad)
#define NPAIR 200       // 400 h values -> 200 tagged 64-bit words

typedef _Float16 f16;
typedef _Float16 half2t __attribute__((ext_vector_type(2)));
typedef unsigned long long u64;
typedef unsigned int u32;

// ---------- math helpers ----------
__device__ __forceinline__ float fexp(float x) {
    return __builtin_amdgcn_exp2f(x * 1.4426950408889634f);
}
__device__ __forceinline__ float sigf(float x) {
    return __builtin_amdgcn_rcpf(1.0f + fexp(-x));
}
__device__ __forceinline__ float tanhf_fast(float x) {
    return 1.0f - 2.0f * __builtin_amdgcn_rcpf(1.0f + fexp(2.0f * x));
}
__device__ __forceinline__ unsigned short f16bits(f16 x) {
    union { f16 h; unsigned short u; } v; v.h = x; return v.u;
}
__device__ __forceinline__ u32 packh2(float a, float b) {
    half2t hv; hv.x = (_Float16)a; hv.y = (_Float16)b;
    return __builtin_bit_cast(u32, hv);
}

#if __has_builtin(__builtin_amdgcn_fdot2)
__device__ __forceinline__ float dot2u(u32 a, u32 b, float c) {
    return __builtin_amdgcn_fdot2(__builtin_bit_cast(half2t, a),
                                  __builtin_bit_cast(half2t, b), c, false);
}
#else
__device__ __forceinline__ float dot2u(u32 a, u32 b, float c) {
    half2t x = __builtin_bit_cast(half2t, a), y = __builtin_bit_cast(half2t, b);
    return fmaf((float)x.y, (float)y.y, fmaf((float)x.x, (float)y.x, c));
}
#endif

// system-scope (sc0 sc1) plain ops: bypass L1/L2, serviced at the IC --
// coherent across XCDs without RMWs or fences.
__device__ __forceinline__ u64 sysload(const u64* p) {
    return __hip_atomic_load(p, __ATOMIC_RELAXED, __HIP_MEMORY_SCOPE_SYSTEM);
}
__device__ __forceinline__ void sysstore(u64* p, u64 v) {
    __hip_atomic_store(p, v, __ATOMIC_RELAXED, __HIP_MEMORY_SCOPE_SYSTEM);
}

// ---------- fused layer-0 gate GEMM (double-buffered) + slot init ----------
// grid (4, 26, 2): y<25 compute G[z][t][r] = emb(t) . Wih0[z][r] + biases
// (embedding gather inlined in the X-stage); y==25,x==0,z==0 runs slot init.
// Double-buffered LDS staging: iteration it+1's global loads issue BEFORE
// iteration it's compute, land in the alternate buffer after -- the global
// round trip (~500cy) hides under the ~700cy compute phase. 1 barrier/iter.
__global__ __launch_bounds__(256) void gemm_l0(
    const int* __restrict__ words, const int* __restrict__ tags,
    const float* __restrict__ wemb, const float* __restrict__ temb,
    const float* __restrict__ Wt,    // Wih0 [2][G4][H]
    const float* __restrict__ bias1, // bih0 [2][G4]
    const float* __restrict__ bias2, // bhh0 [2][G4]
    float* __restrict__ out,         // Gb [2][T][G4]
    const float* __restrict__ h0, u64* sA, u64* sB) {
    const int tid = threadIdx.x;
    const int z = blockIdx.z;
    const int t0 = blockIdx.x * 64, r0 = blockIdx.y * 64;

    if (r0 >= G4) {
        if (blockIdx.x != 0 || z != 0) return;
        const int TOT = 2 * 2 * NPAIR;
        for (int i = tid; i < TOT; i += 256) { sA[i] = 0xFFFFULL; sB[i] = 0xFFFFULL; }
        __syncthreads();
        for (int p = tid; p < 2 * NPAIR; p += 256) {
            int d = p / NPAIR, pr = p - d * NPAIR;
            size_t off = (size_t)(d * 2 + 0) * NPAIR + pr;   // parity 0, tag 0
            f16 a0 = (f16)h0[d * H + 2 * pr], b0 = (f16)h0[d * H + 2 * pr + 1];
            sA[off] = 0ULL | ((u64)f16bits(a0) << 16) | ((u64)f16bits(b0) << 32);
            f16 a1 = (f16)h0[2 * H + d * H + 2 * pr], b1 = (f16)h0[2 * H + d * H + 2 * pr + 1];
            sB[off] = 0ULL | ((u64)f16bits(a1) << 16) | ((u64)f16bits(b1) << 32);
        }
        return;
    }

    __shared__ float Xs[2][64][17];
    __shared__ float Ws[2][64][17];
    __shared__ int wsh[64], tsh[64];
    const float* Wtz = Wt + (size_t)z * G4 * H;
    const float* b1 = bias1 + (size_t)z * G4;
    const float* b2 = bias2 + (size_t)z * G4;
    float* outz = out + (size_t)z * T * G4;
    const int lr = tid >> 2, kq = (tid & 3) * 4;
    const int ti = tid >> 4, rj = tid & 15;
    if (tid < 64) { wsh[tid] = words[t0 + tid]; tsh[tid] = tags[t0 + tid]; }
    __syncthreads();
    // preload iter 0
    {
        float4 xv = (kq < WD)
            ? *(const float4*)(wemb + (size_t)wsh[lr] * WD + kq)
            : *(const float4*)(temb + (size_t)tsh[lr] * TD + (kq - WD));
        Xs[0][lr][kq + 0] = xv.x; Xs[0][lr][kq + 1] = xv.y;
        Xs[0][lr][kq + 2] = xv.z; Xs[0][lr][kq + 3] = xv.w;
        float4 wv = *(const float4*)(Wtz + (size_t)(r0 + lr) * H + kq);
        Ws[0][lr][kq + 0] = wv.x; Ws[0][lr][kq + 1] = wv.y;
        Ws[0][lr][kq + 2] = wv.z; Ws[0][lr][kq + 3] = wv.w;
    }
    __syncthreads();
    float acc[4][4] = {};
    const int niter = H / 16;   // 25
    for (int it = 0; it < niter; ++it) {
        const int buf = it & 1;
        const bool more = (it + 1 < niter);
        float4 xn, wn;
        if (more) {
            int k = ((it + 1) << 4) + kq;
            xn = (k < WD)
                ? *(const float4*)(wemb + (size_t)wsh[lr] * WD + k)
                : *(const float4*)(temb + (size_t)tsh[lr] * TD + (k - WD));
            wn = *(const float4*)(Wtz + (size_t)(r0 + lr) * H + k);
        }
#pragma unroll
        for (int kk = 0; kk < 16; kk++) {
            float xr[4], wr[4];
#pragma unroll
            for (int m = 0; m < 4; m++) xr[m] = Xs[buf][ti * 4 + m][kk];
#pragma unroll
            for (int n = 0; n < 4; n++) wr[n] = Ws[buf][rj * 4 + n][kk];
#pragma unroll
            for (int m = 0; m < 4; m++)
#pragma unroll
                for (int n = 0; n < 4; n++)
                    acc[m][n] = fmaf(xr[m], wr[n], acc[m][n]);
        }
        if (more) {
            Xs[buf ^ 1][lr][kq + 0] = xn.x; Xs[buf ^ 1][lr][kq + 1] = xn.y;
            Xs[buf ^ 1][lr][kq + 2] = xn.z; Xs[buf ^ 1][lr][kq + 3] = xn.w;
            Ws[buf ^ 1][lr][kq + 0] = wn.x; Ws[buf ^ 1][lr][kq + 1] = wn.y;
            Ws[buf ^ 1][lr][kq + 2] = wn.z; Ws[buf ^ 1][lr][kq + 3] = wn.w;
        }
        __syncthreads();
    }
    int rq = r0 + rj * 4;
    {
        float b[4];
#pragma unroll
        for (int n = 0; n < 4; n++) { int r = rq + n; b[n] = b1[r] + b2[r]; }
#pragma unroll
        for (int m = 0; m < 4; m++) {
            int t = t0 + ti * 4 + m;
            float4 o;
            o.x = acc[m][0] + b[0]; o.y = acc[m][1] + b[1];
            o.z = acc[m][2] + b[2]; o.w = acc[m][3] + b[3];
            *(float4*)(outz + (size_t)t * G4 + rq) = o;
        }
    }
}

// ---------- z-batched GEMM, double-buffered LDS staging ----------
__global__ __launch_bounds__(256) void gemm_tnz(
    const float* __restrict__ X, int ldx,
    const float* __restrict__ Wt, long wz, int ldw, int wofs0, int wstep,
    const float* __restrict__ bias1, int b1zs, int b1mask,
    const float* __restrict__ bias2, int b2zs, int b2mask,
    float* __restrict__ out, int ldo, long ozs, int Rt, int K) {
    __shared__ float Xs[2][64][17];
    __shared__ float Ws[2][64][17];
    const int tid = threadIdx.x;
    const int z = blockIdx.z;
    const float* Wtz = Wt + (size_t)z * wz;
    const int wofs = wofs0 + z * wstep;
    const float* b1 = (bias1 && ((b1mask >> z) & 1)) ? bias1 + (size_t)z * b1zs : nullptr;
    const float* b2 = (bias2 && ((b2mask >> z) & 1)) ? bias2 + (size_t)z * b2zs : nullptr;
    float* outz = out + (size_t)z * ozs;
    const int t0 = blockIdx.x * 64, r0 = blockIdx.y * 64;
    const int lr = tid >> 2, kq = (tid & 3) * 4;
    const int ti = tid >> 4, rj = tid & 15;
    // preload iter 0
    {
        float4 xv = *(const float4*)(X + (size_t)(t0 + lr) * ldx + kq);
        Xs[0][lr][kq + 0] = xv.x; Xs[0][lr][kq + 1] = xv.y;
        Xs[0][lr][kq + 2] = xv.z; Xs[0][lr][kq + 3] = xv.w;
        int r = r0 + lr;
        float4 wv = make_float4(0.f, 0.f, 0.f, 0.f);
        if (r < Rt) wv = *(const float4*)(Wtz + (size_t)r * ldw + wofs + kq);
        Ws[0][lr][kq + 0] = wv.x; Ws[0][lr][kq + 1] = wv.y;
        Ws[0][lr][kq + 2] = wv.z; Ws[0][lr][kq + 3] = wv.w;
    }
    __syncthreads();
    float acc[4][4] = {};
    const int niter = K >> 4;
    for (int it = 0; it < niter; ++it) {
        const int buf = it & 1;
        const bool more = (it + 1 < niter);
        float4 xn, wn;
        if (more) {
            int k0 = (it + 1) << 4;
            xn = *(const float4*)(X + (size_t)(t0 + lr) * ldx + k0 + kq);
            int r = r0 + lr;
            wn = make_float4(0.f, 0.f, 0.f, 0.f);
            if (r < Rt) wn = *(const float4*)(Wtz + (size_t)r * ldw + wofs + k0 + kq);
        }
#pragma unroll
        for (int kk = 0; kk < 16; kk++) {
            float xr[4], wr[4];
#pragma unroll
            for (int m = 0; m < 4; m++) xr[m] = Xs[buf][ti * 4 + m][kk];
#pragma unroll
            for (int n = 0; n < 4; n++) wr[n] = Ws[buf][rj * 4 + n][kk];
#pragma unroll
            for (int m = 0; m < 4; m++)
#pragma unroll
                for (int n = 0; n < 4; n++)
                    acc[m][n] = fmaf(xr[m], wr[n], acc[m][n]);
        }
        if (more) {
            Xs[buf ^ 1][lr][kq + 0] = xn.x; Xs[buf ^ 1][lr][kq + 1] = xn.y;
            Xs[buf ^ 1][lr][kq + 2] = xn.z; Xs[buf ^ 1][lr][kq + 3] = xn.w;
            Ws[buf ^ 1][lr][kq + 0] = wn.x; Ws[buf ^ 1][lr][kq + 1] = wn.y;
            Ws[buf ^ 1][lr][kq + 2] = wn.z; Ws[buf ^ 1][lr][kq + 3] = wn.w;
        }
        __syncthreads();
    }
    int rq = r0 + rj * 4;
    if (rq < Rt) {
        float b[4];
#pragma unroll
        for (int n = 0; n < 4; n++) {
            int r = rq + n;
            b[n] = (b1 ? b1[r] : 0.f) + (b2 ? b2[r] : 0.f);
        }
#pragma unroll
        for (int m = 0; m < 4; m++) {
            int t = t0 + ti * 4 + m;
            float4 o;
            o.x = acc[m][0] + b[0]; o.y = acc[m][1] + b[1];
            o.z = acc[m][2] + b[2]; o.w = acc[m][3] + b[3];
            *(float4*)(outz + (size_t)t * ldo + rq) = o;
        }
    }
}

// ---------- persistent LSTM layer v8 (R0/R8-proven, best known: 508us/layer) ----------
// grid = 50 blocks (dir = b/25, blk = b%25), 512 threads. Block owns h rows
// [blk*16,+16) = 64 gate-rows. Weights live in LDS (50.5 KiB, loaded once).
// tid<256: workers, 4 per gate-row; tid in [256,448): pollers for the 192
// foreign tagged words (IC-scope sc0/sc1 scheme); tid>=448: G stagers.
// Wave 0 does gate math + publish via intra-wave shuffles. 2 barriers/step.
__global__ __launch_bounds__(512, 1) void lstm_layer8(
    const float* __restrict__ G,     // [2][T][G4] gate inputs, biases folded
    const float* __restrict__ Whh,   // [2][G4][H]
    const float* __restrict__ c0l,   // [2][H] this layer
    float* __restrict__ xout,        // [T][2H]
    u64* __restrict__ slots) {       // [2][2][NPAIR]
    const int role = blockIdx.x;
    const int dir = role / NBLK_D, blk = role - dir * NBLK_D;
    const int tid = threadIdx.x;
    const float* Wd = Whh + (size_t)dir * G4 * H;
    const float* Gd = G + (size_t)dir * T * G4;
    u64* sd = slots + (size_t)dir * 2 * NPAIR;

    __shared__ u32 wlds[GR * WSTR];            // 64 rows x 202 u32 = 50.5 KiB
    __shared__ __align__(16) u32 hsh[NPAIR];   // h_s as 200 packed half2
    __shared__ float gsum[GR];                 // per-gate-row matvec sums
    __shared__ float gsh[2][GR];               // staged G, double-buffered

    // ---- one-time: pack weights fp32 -> half2 into LDS ----
    for (int idx = tid; idx < GR * 100; idx += 512) {
        int row = idx / 100, c4 = idx - row * 100;
        int g = row >> 4, r = row & 15;
        const float4* src = (const float4*)(Wd + (size_t)(g * H + blk * HB + r) * H);
        float4 f = src[c4];
        *(uint2*)&wlds[row * WSTR + c4 * 2] =
            make_uint2(packh2(f.x, f.y), packh2(f.z, f.w));
    }
    // pre-stage G(0); own h0 words into LDS
    if (tid >= 448) {
        int i = tid - 448, gg = i >> 4, rr = i & 15;
        int tt0 = dir ? (T - 1) : 0;
        gsh[0][i] = Gd[(size_t)tt0 * G4 + gg * H + blk * HB + rr];
    } else if (tid < 8) {
        u64 v = sysload(sd + blk * 8 + tid);       // parity 0, tag 0
        hsh[blk * 8 + tid] = (u32)(v >> 16);
    }
    float c = (tid < 64) ? c0l[dir * H + blk * HB + (tid & 15)] : 0.f;
    __syncthreads();

#pragma clang loop unroll(disable)
    for (int s = 0; s < T; ++s) {
        if (tid >= 256 && tid < 448) {
            // poller: one foreign word (parity s&1, tag s)
            int f = tid - 256;
            int widx = f + (f >= blk * 8 ? 8 : 0);
            u64* src = sd + (size_t)(s & 1) * NPAIR + widx;
            u64 v = sysload(src);
            int spins = 0;
            while ((unsigned)(v & 0xFFFFULL) != (unsigned)s) {
                if (++spins > 16384) {
                    v = __hip_atomic_fetch_add(src, 0ULL, __ATOMIC_RELAXED,
                                               __HIP_MEMORY_SCOPE_AGENT);
                } else {
                    v = sysload(src);
                }
            }
            hsh[widx] = (u32)(v >> 16);
        } else if (tid >= 448) {
            // stager: G(s+1) into the other parity half
            int sn = (s + 1 < T) ? (s + 1) : s;
            int tt = dir ? (T - 1 - sn) : sn;
            int i = tid - 448, gg = i >> 4, rr = i & 15;
            gsh[(s + 1) & 1][i] = Gd[(size_t)tt * G4 + gg * H + blk * HB + rr];
        }
        __syncthreads();   // (A) h_s complete in LDS

        if (tid < 256) {
            const int row = tid >> 2, sl = tid & 3;
            const u32* wp = &wlds[row * WSTR + sl * 50];
            const u32* hp = &hsh[sl * 50];
            float a0 = 0.f, a1 = 0.f, a2 = 0.f, a3 = 0.f;
#pragma unroll
            for (int i = 0; i < 12; ++i) {
                uint2 wv0 = *(const uint2*)&wp[4 * i];
                uint2 hv0 = *(const uint2*)&hp[4 * i];
                uint2 wv1 = *(const uint2*)&wp[4 * i + 2];
                uint2 hv1 = *(const uint2*)&hp[4 * i + 2];
                a0 = dot2u(wv0.x, hv0.x, a0);
                a1 = dot2u(wv0.y, hv0.y, a1);
                a2 = dot2u(wv1.x, hv1.x, a2);
                a3 = dot2u(wv1.y, hv1.y, a3);
            }
            {
                uint2 wv = *(const uint2*)&wp[48];
                uint2 hv = *(const uint2*)&hp[48];
                a0 = dot2u(wv.x, hv.x, a0);
                a1 = dot2u(wv.y, hv.y, a1);
            }
            float a = (a0 + a1) + (a2 + a3);
            a += __shfl_xor(a, 1);    // combine the 4 k-slices (adjacent lanes)
            a += __shfl_xor(a, 2);
            if (sl == 0) gsum[row] = a;
        }
        __syncthreads();   // (B) sums ready

        if (tid < 64) {    // wave 0: gate math + publish, intra-wave only
            const int r = tid & 15;
            const float* gc = gsh[s & 1];
            float iv = gsum[r]      + gc[r];
            float fv = gsum[16 + r] + gc[16 + r];
            float gv = gsum[32 + r] + gc[32 + r];
            float ov = gsum[48 + r] + gc[48 + r];
            float cn = sigf(fv) * c + sigf(iv) * tanhf_fast(gv);
            c = cn;
            float hn = sigf(ov) * tanhf_fast(cn);
            u32 hb = (u32)f16bits((f16)hn);
            u32 lo = __shfl(hb, (2 * tid) & 63);
            u32 hi = __shfl(hb, (2 * tid + 1) & 63);
            if (tid < 8) {
                u32 pk = (lo & 0xFFFFu) | (hi << 16);
                hsh[blk * 8 + tid] = pk;   // own slice of h_{s+1}, LDS fast-path
                sysstore(sd + (size_t)((s + 1) & 1) * NPAIR + blk * 8 + tid,
                         (u64)(unsigned)(s + 1) | ((u64)pk << 16));
            }
            const int tt = dir ? (T - 1 - s) : s;
            if (tid < 16)
                xout[(size_t)tt * (2 * H) + dir * H + blk * HB + tid] = hn;
        }
    }
}

// ---------- fused pairwise scorer ----------
__global__ __launch_bounds__(256) void scores_k(
    const float* __restrict__ pi, const float* __restrict__ pj,
    const float* __restrict__ w2, const float* __restrict__ b2p,
    float* __restrict__ out) {
    __shared__ float Ps[16][401];
    __shared__ float Qs[16][401];
    __shared__ float w2s[400];
    const int tid = threadIdx.x;
    const int i0 = blockIdx.y * 16, j0 = blockIdx.x * 16;
    for (int r = 0; r < 16; r++) {
        for (int k = tid; k < MLP_H; k += 256) {
            Ps[r][k] = pi[(size_t)(i0 + r) * MLP_H + k];
            Qs[r][k] = pj[(size_t)(j0 + r) * MLP_H + k];
        }
    }
    for (int k = tid; k < MLP_H; k += 256) w2s[k] = w2[k];
    __syncthreads();
    const int ti = tid >> 4, tj = tid & 15;
    float acc = 0.f;
#pragma unroll 4
    for (int k = 0; k < MLP_H; k++) {
        float x = Ps[ti][k] + Qs[tj][k];
        acc = fmaf(w2s[k], tanhf_fast(x), acc);
    }
    const int i = i0 + ti, j = j0 + tj;
    out[(size_t)i * T + j] = (i == j) ? 0.f : (acc + b2p[0]);
}

extern "C" void kernel_launch(void* const* d_in, const int* in_sizes, int n_in,
                              void* d_out, int out_size, void* d_ws, size_t ws_size,
                              hipStream_t stream) {
    const int*   words = (const int*)d_in[0];
    const int*   tags  = (const int*)d_in[1];
    const float* wemb  = (const float*)d_in[2];
    const float* temb  = (const float*)d_in[3];
    const float* Wih0  = (const float*)d_in[4];
    const float* Whh0  = (const float*)d_in[5];
    const float* bih0  = (const float*)d_in[6];
    const float* bhh0  = (const float*)d_in[7];
    const float* Wih1  = (const float*)d_in[8];
    const float* Whh1  = (const float*)d_in[9];
    const float* bih1  = (const float*)d_in[10];
    const float* bhh1  = (const float*)d_in[11];
    const float* W1    = (const float*)d_in[12];
    const float* b1    = (const float*)d_in[13];
    const float* W2    = (const float*)d_in[14];
    const float* b2    = (const float*)d_in[15];
    const float* h0    = (const float*)d_in[16];
    const float* c0    = (const float*)d_in[17];
    float* out = (float*)d_out;

    float* W = (float*)d_ws;
    float* x1   = W + 102400;        // 256*800
    float* hvec = W + 307200;        // 256*800
    float* Gb   = W + 512000;        // 2*256*1600 (reused for both layers)
    float* pi   = W + 1331200;       // 256*400
    float* pj   = W + 1433600;       // 256*400 (pj = pi + 102400)
    u64* slotsA = (u64*)W;                               // 800 u64
    u64* slotsB = (u64*)(W + 2048);                      // 800 u64

    // 1. layer-0 gate inputs with fused embedding gather + slot init
    gemm_l0<<<dim3(4, 26, 2), 256, 0, stream>>>(
        words, tags, wemb, temb, Wih0, bih0, bhh0, Gb, h0, slotsA, slotsB);

    // 2. LSTM layer 0
    lstm_layer8<<<2 * NBLK_D, 512, 0, stream>>>(Gb, Whh0, c0, x1, slotsA);

    // 3. layer-1 gate inputs (K=800), BOTH dirs in one launch
    gemm_tnz<<<dim3(4, 25, 2), 256, 0, stream>>>(
        x1, 2 * H, Wih1, (long)G4 * 2 * H, 2 * H, 0, 0,
        bih1, G4, 3, bhh1, G4, 3,
        Gb, G4, (long)T * G4, G4, 2 * H);

    // 4. LSTM layer 1
    lstm_layer8<<<2 * NBLK_D, 512, 0, stream>>>(Gb, Whh1, c0 + 2 * H, hvec, slotsB);

    // 5. pi and pj in ONE launch (z: 0 -> pi with b1, 1 -> pj, W1 col-offset 2H)
    gemm_tnz<<<dim3(4, 7, 2), 256, 0, stream>>>(
        hvec, 2 * H, W1, 0L, G4, 0, 2 * H,
        b1, 0, 1, nullptr, 0, 0,
        pi, MLP_H, 102400L, MLP_H, 2 * H);

    // 6. fused pairwise scores
    scores_k<<<dim3(16, 16), 256, 0, stream>>>(pi, pj, W2, b2, out);
}